// Round 4
// baseline (147.691 us; speedup 1.0000x reference)
//
#include <hip/hip_runtime.h>
#include <math.h>

// DIN fused, round 4. Pipelined gathers + 3 barriers/b + bf16 pre-swizzled comb.
//  k0 prep: A'=W1a+W1c, D'=W1d as [h][d] bf16; Bm=W1b-W1c as [d][h] bf16;
//           fw1^T pre-swizzled bf16 image.
//  k1 main: 8 b's/block, gather for b+1 in flight during b's compute.
//  k2 FC:   relu(comb@fw1+b1)@fw2+b2 via MFMA, 16 b's/block, all-LDS staged.

#define S_LEN 200
#define S_PAD 208

typedef __attribute__((ext_vector_type(8))) short short8;
typedef __attribute__((ext_vector_type(4))) float f32x4;

__device__ __forceinline__ unsigned short f2b(float f) {
  union { float f; unsigned u; } x; x.f = f;
  unsigned r = x.u + 0x7fffu + ((x.u >> 16) & 1u);
  return (unsigned short)(r >> 16);
}
__device__ __forceinline__ float b2f(unsigned short h) {
  union { unsigned u; float f; } x; x.u = ((unsigned)h) << 16; return x.f;
}

// [row][64] bf16 tile, row stride 128 B -> ushort index (XOR row&7 into byte b4..6)
__device__ __forceinline__ int swzB(int row, int col) {
  int byte = row * 128 + col * 2;
  byte ^= (row & 7) << 4;
  return byte >> 1;
}
// [row][256] bf16 tile, row stride 512 B -> ushort index
__device__ __forceinline__ int swzW(int row, int col) {
  int byte = row * 512 + col * 2;
  byte ^= (row & 7) << 4;
  return byte >> 1;
}

__device__ __forceinline__ void async_g2l_16(const void* g, void* l) {
  __builtin_amdgcn_global_load_lds(
      (const __attribute__((address_space(1))) void*)g,
      (__attribute__((address_space(3))) void*)l, 16, 0, 0);
}

// ---------------- workspace layout (bytes) ----------------
// combS bf16-swz [256 tiles][16][256] : 0 .. 2097152
#define WS_COMB 0
#define WS_AT   2097152
#define WS_DT   2113536
#define WS_BM   2129920
#define WS_FW1T 2146304

// ================= k0: prep =================
__global__ __launch_bounds__(256)
void din_prep(const float* __restrict__ aw1, const float* __restrict__ fw1,
              char* __restrict__ ws)
{
  unsigned short* AT   = (unsigned short*)(ws + WS_AT);
  unsigned short* DT   = (unsigned short*)(ws + WS_DT);
  unsigned short* Bm   = (unsigned short*)(ws + WS_BM);
  unsigned short* FW1T = (unsigned short*)(ws + WS_FW1T);
  const int blk = blockIdx.x, tid = threadIdx.x;

  if (blk < 32) {               // A'T, D'T : [h][d]
    const int i = blk * 256 + tid;
    const int h = i >> 6, d = i & 63;
    const float a = aw1[d * 128 + h];
    const float c = aw1[(128 + d) * 128 + h];
    const float dd = aw1[(192 + d) * 128 + h];
    AT[i] = f2b(a + c);
    DT[i] = f2b(dd);
  } else if (blk < 64) {        // Bm : [d][h]
    const int j = (blk - 32) * 256 + tid;
    const int d = j >> 7, h = j & 127;
    Bm[j] = f2b(aw1[(64 + d) * 128 + h] - aw1[(128 + d) * 128 + h]);
  } else {                      // fw1T swizzled image
    const int i = (blk - 64) * 256 + tid;
    const int o = 2 * i;
    const int h = o >> 9;
    const int rr = o & 511;
    const int d = (rr ^ ((h & 7) << 4)) >> 1;
    FW1T[i] = f2b(fw1[d * 128 + h]);
  }
}

// ================= k1: main =================
__global__ __launch_bounds__(512, 4)
void din_main(const int* __restrict__ uf, const int* __restrict__ tif,
              const int* __restrict__ bseq,
              const float* __restrict__ e0, const float* __restrict__ e1,
              const float* __restrict__ ei,
              const float* __restrict__ ab1, const float* __restrict__ aw2,
              char* __restrict__ ws)
{
  __shared__ unsigned short sBuf[2][13312];  // 2x 26624 B; buf1 aliases Bm stage
  __shared__ int   sIdx[1600];
  __shared__ float sT[512];
  __shared__ float sCH[1024];
  __shared__ float sPart[8 * S_PAD];
  __shared__ float sScores[S_PAD];
  __shared__ float sPool[2][512];
  __shared__ float sRedS[8];

  unsigned short* combS = (unsigned short*)(ws + WS_COMB);
  const unsigned short* ATws = (const unsigned short*)(ws + WS_AT);
  const unsigned short* DTws = (const unsigned short*)(ws + WS_DT);

  const int tid  = threadIdx.x;
  const int lane = tid & 63;
  const int wv   = tid >> 6;
  const int bb   = blockIdx.x * 8;

  // ---- prologue ----
  for (int k = tid; k < 1600; k += 512) sIdx[k] = bseq[bb * 200 + k];
  {
    const int g = tid >> 6, d = tid & 63, b = bb + g;
    const int u0 = uf[2 * b], u1 = uf[2 * b + 1], ti = tif[b];
    const float tv = ei[(size_t)ti * 64 + d];
    sT[g * 64 + d] = tv;
    unsigned short* ct = combS + (size_t)(b >> 4) * 4096;
    const int row = b & 15;
    ct[swzW(row, 192 + d)] = f2b(tv);
    ct[swzW(row, d)]       = f2b(e0[(size_t)u0 * 64 + d]);
    ct[swzW(row, 64 + d)]  = f2b(e1[(size_t)u1 * 64 + d]);
  }
  if (tid < 128) {   // zero pad rows 200..207 in both buffers (once)
    const int row = 200 + (tid >> 4), c = (tid & 15) * 4;
    ushort4 z = {0, 0, 0, 0};
    *(ushort4*)&sBuf[0][swzB(row, c)] = z;
    *(ushort4*)&sBuf[1][swzB(row, c)] = z;
  }
  {  // stage Bm (16 KB) into sBuf[1] low region (disjoint from pad rows)
    char* dst = (char*)sBuf[1];
    const char* src = ws + WS_BM;
    async_g2l_16(src + tid * 16, dst + tid * 16);
    async_g2l_16(src + 8192 + tid * 16, dst + 8192 + tid * 16);
  }
  const int hl = lane & 15, rq = lane >> 4;
  const int h  = wv * 16 + hl;
  const short8 aT0 = *(const short8*)(ATws + h * 64 + rq * 8);
  const short8 aT1 = *(const short8*)(ATws + h * 64 + 32 + rq * 8);
  const short8 dT0 = *(const short8*)(DTws + h * 64 + rq * 8);
  const short8 dT1 = *(const short8*)(DTws + h * 64 + 32 + rq * 8);
  const float w2h = aw2[h];
  const float abv = ab1[h];

  __syncthreads();  // A: sIdx/sT/Bm/pad ready

  // issue gathers for g=0 (in flight under cH compute)
  float4 gv[7];
#pragma unroll
  for (int it = 0; it < 7; ++it) {
    const int row = it * 32 + (tid >> 4);
    if (row < S_LEN) {
      const int idx = sIdx[row];
      gv[it] = *(const float4*)(ei + (size_t)idx * 64 + (tid & 15) * 4);
    }
  }

  // cH[b][h2] = t[b] . Bm[:,h2]  (reads sBuf[1])
  {
    const unsigned short* sBm = sBuf[1];
    const int h2 = tid & 127, bq = tid >> 7;
    float c0 = 0.f, c1 = 0.f;
    const float* t0 = sT + (2 * bq) * 64;
    const float* t1 = sT + (2 * bq + 1) * 64;
#pragma unroll 8
    for (int d = 0; d < 64; ++d) {
      const float bmv = b2f(sBm[d * 128 + h2]);
      c0 = fmaf(t0[d], bmv, c0);
      c1 = fmaf(t1[d], bmv, c1);
    }
    sCH[(2 * bq) * 128 + h2] = c0;
    sCH[(2 * bq + 1) * 128 + h2] = c1;
  }

  float invS_prev = 0.f;

  // ---- per-b loop, 3 barriers each ----
  for (int g = 0; g < 8; ++g) {
    unsigned short* beh = sBuf[g & 1];

    // commit current gathers to LDS (bf16, swizzled); vmcnt wait was hidden
#pragma unroll
    for (int it = 0; it < 7; ++it) {
      const int row = it * 32 + (tid >> 4);
      if (row < S_LEN) {
        ushort4 pk;
        pk.x = f2b(gv[it].x); pk.y = f2b(gv[it].y);
        pk.z = f2b(gv[it].z); pk.w = f2b(gv[it].w);
        *(ushort4*)&beh[swzB(row, (tid & 15) * 4)] = pk;
      }
    }

    // issue next-b gathers (stay in flight through this b's compute)
    float4 gvn[7];
    if (g < 7) {
#pragma unroll
      for (int it = 0; it < 7; ++it) {
        const int row = it * 32 + (tid >> 4);
        if (row < S_LEN) {
          const int idx = sIdx[(g + 1) * 200 + row];
          gvn[it] = *(const float4*)(ei + (size_t)idx * 64 + (tid & 15) * 4);
        }
      }
    }

    // per-b B fragments: w = aT + t (.) dT
    short8 w0, w1;
    {
      const float* tb = sT + g * 64;
      const float4 ta0 = *(const float4*)(tb + rq * 8);
      const float4 tc0 = *(const float4*)(tb + rq * 8 + 4);
      const float4 ta1 = *(const float4*)(tb + 32 + rq * 8);
      const float4 tc1 = *(const float4*)(tb + 32 + rq * 8 + 4);
      const float tt0[8] = {ta0.x, ta0.y, ta0.z, ta0.w, tc0.x, tc0.y, tc0.z, tc0.w};
      const float tt1[8] = {ta1.x, ta1.y, ta1.z, ta1.w, tc1.x, tc1.y, tc1.z, tc1.w};
      union { short8 s; unsigned u[4]; } o0, o1;
#pragma unroll
      for (int p = 0; p < 4; ++p) {
        float lo = fmaf(tt0[2*p],   b2f((unsigned short)dT0[2*p]),   b2f((unsigned short)aT0[2*p]));
        float hi = fmaf(tt0[2*p+1], b2f((unsigned short)dT0[2*p+1]), b2f((unsigned short)aT0[2*p+1]));
        o0.u[p] = (unsigned)f2b(lo) | ((unsigned)f2b(hi) << 16);
        lo = fmaf(tt1[2*p],   b2f((unsigned short)dT1[2*p]),   b2f((unsigned short)aT1[2*p]));
        hi = fmaf(tt1[2*p+1], b2f((unsigned short)dT1[2*p+1]), b2f((unsigned short)aT1[2*p+1]));
        o1.u[p] = (unsigned)f2b(lo) | ((unsigned)f2b(hi) << 16);
      }
      w0 = o0.s; w1 = o1.s;
    }

    __syncthreads();  // (1) beh ready; sCH ready; prev sPool ready

    // deferred interest write for b-1
    if (g > 0 && tid < 64) {
      const float* pp = sPool[(g - 1) & 1];
      float a = 0.f;
#pragma unroll
      for (int sg = 0; sg < 8; ++sg) a += pp[sg * 64 + tid];
      const int b = bb + g - 1;
      combS[(size_t)(b >> 4) * 4096 + swzW(b & 15, 128 + tid)] = f2b(a * invS_prev);
    }

    const float cHh = sCH[g * 128 + h] + abv;

    // scores via MFMA: wave wv owns h-cols [wv*16, wv*16+16)
#pragma unroll 1
    for (int mt = 0; mt < 13; ++mt) {
      f32x4 acc = {0.f, 0.f, 0.f, 0.f};
      const short8 av0 = *(const short8*)&beh[swzB(mt * 16 + hl, rq * 8)];
      acc = __builtin_amdgcn_mfma_f32_16x16x32_bf16(av0, w0, acc, 0, 0, 0);
      const short8 av1 = *(const short8*)&beh[swzB(mt * 16 + hl, 32 + rq * 8)];
      acc = __builtin_amdgcn_mfma_f32_16x16x32_bf16(av1, w1, acc, 0, 0, 0);
#pragma unroll
      for (int r = 0; r < 4; ++r) {
        float v = fmaxf(acc[r] + cHh, 0.f) * w2h;
        v += __shfl_xor(v, 1, 64);
        v += __shfl_xor(v, 2, 64);
        v += __shfl_xor(v, 4, 64);
        v += __shfl_xor(v, 8, 64);
        if (hl == 0) sPart[wv * S_PAD + mt * 16 + rq * 4 + r] = v;
      }
    }
    __syncthreads();  // (2) sPart ready

    // softmax (no max-shift: |scores| << 1 for this data; shift-invariant)
    float e = 0.f;
    if (tid < S_LEN) {
      const float a0 = sPart[tid]             + sPart[S_PAD + tid];
      const float a1 = sPart[2 * S_PAD + tid] + sPart[3 * S_PAD + tid];
      const float a2 = sPart[4 * S_PAD + tid] + sPart[5 * S_PAD + tid];
      const float a3 = sPart[6 * S_PAD + tid] + sPart[7 * S_PAD + tid];
      e = __expf((a0 + a1) + (a2 + a3));
      sScores[tid] = e;
    }
    if (wv < 4) {
      float s = e;
#pragma unroll
      for (int mm = 32; mm; mm >>= 1) s += __shfl_xor(s, mm, 64);
      if (lane == 0) sRedS[wv] = s;
    }
    __syncthreads();  // (3) sScores + sums ready

    const float invS = 1.f / (sRedS[0] + sRedS[1] + sRedS[2] + sRedS[3]);

    // pooling
    {
      const int sg = tid >> 6, ecol = tid & 63;
      float a = 0.f;
#pragma unroll 5
      for (int k = 0; k < 25; ++k) {
        const int s = sg + k * 8;
        a = fmaf(sScores[s], b2f(beh[swzB(s, ecol)]), a);
      }
      sPool[g & 1][sg * 64 + ecol] = a;
    }
    invS_prev = invS;

    if (g < 7) {
#pragma unroll
      for (int it = 0; it < 7; ++it) gv[it] = gvn[it];
    }
  }

  __syncthreads();
  if (tid < 64) {  // tail interest write for b = bb+7
    const float* pp = sPool[1];
    float a = 0.f;
#pragma unroll
    for (int sg = 0; sg < 8; ++sg) a += pp[sg * 64 + tid];
    const int b = bb + 7;
    combS[(size_t)(b >> 4) * 4096 + swzW(b & 15, 128 + tid)] = f2b(a * invS_prev);
  }
}

// ================= k2: FC head =================
__global__ __launch_bounds__(256, 2)
void din_fc(const float* __restrict__ fb1, const float* __restrict__ fw2,
            const float* __restrict__ fb2, const char* __restrict__ ws,
            float* __restrict__ out)
{
  __shared__ unsigned short sW[32768];   // fw1T swizzled image, 64 KB
  __shared__ unsigned short sA[4096];    // comb tile (pre-swizzled bf16), 8 KB
  __shared__ float sO[64];

  const int tid  = threadIdx.x;
  const int lane = tid & 63;
  const int wv   = tid >> 6;
  const int bb   = blockIdx.x * 16;

  {
    const char* srcW = ws + WS_FW1T;
    char* dstW = (char*)sW;
#pragma unroll
    for (int it = 0; it < 16; ++it)
      async_g2l_16(srcW + it * 4096 + tid * 16, dstW + it * 4096 + tid * 16);
    const char* srcA = ws + WS_COMB + (size_t)blockIdx.x * 8192;
    char* dstA = (char*)sA;
    async_g2l_16(srcA + tid * 16, dstA + tid * 16);
    async_g2l_16(srcA + 4096 + tid * 16, dstA + 4096 + tid * 16);
  }
  __syncthreads();

  const int hl = lane & 15, rq = lane >> 4;
  const int h0 = wv * 32 + hl, h1 = h0 + 16;
  f32x4 acc0 = {0.f, 0.f, 0.f, 0.f};
  f32x4 acc1 = {0.f, 0.f, 0.f, 0.f};
#pragma unroll
  for (int kk = 0; kk < 8; ++kk) {
    const short8 av = *(const short8*)&sA[swzW(hl, kk * 32 + rq * 8)];
    const short8 b0 = *(const short8*)&sW[swzW(h0, kk * 32 + rq * 8)];
    const short8 b1 = *(const short8*)&sW[swzW(h1, kk * 32 + rq * 8)];
    acc0 = __builtin_amdgcn_mfma_f32_16x16x32_bf16(av, b0, acc0, 0, 0, 0);
    acc1 = __builtin_amdgcn_mfma_f32_16x16x32_bf16(av, b1, acc1, 0, 0, 0);
  }
  const float fb10 = fb1[h0], fb11 = fb1[h1];
  const float fw20 = fw2[h0], fw21 = fw2[h1];
#pragma unroll
  for (int r = 0; r < 4; ++r) {
    float v = fmaxf(acc0[r] + fb10, 0.f) * fw20
            + fmaxf(acc1[r] + fb11, 0.f) * fw21;
    v += __shfl_xor(v, 1, 64);
    v += __shfl_xor(v, 2, 64);
    v += __shfl_xor(v, 4, 64);
    v += __shfl_xor(v, 8, 64);
    if (hl == 0) sO[wv * 16 + rq * 4 + r] = v;
  }
  __syncthreads();
  if (tid < 16)
    out[bb + tid] = sO[tid] + sO[16 + tid] + sO[32 + tid] + sO[48 + tid] + fb2[0];
}

extern "C" void kernel_launch(void* const* d_in, const int* in_sizes, int n_in,
                              void* d_out, int out_size, void* d_ws, size_t ws_size,
                              hipStream_t stream) {
  const int*   uf   = (const int*)d_in[0];
  const int*   tif  = (const int*)d_in[1];
  const int*   bseq = (const int*)d_in[2];
  const float* e0   = (const float*)d_in[3];
  const float* e1   = (const float*)d_in[4];
  const float* ei   = (const float*)d_in[5];
  const float* aw1  = (const float*)d_in[6];
  const float* ab1  = (const float*)d_in[7];
  const float* aw2  = (const float*)d_in[8];
  // d_in[9] = ab2 (unused: softmax shift-invariant)
  const float* fw1  = (const float*)d_in[10];
  const float* fb1  = (const float*)d_in[11];
  const float* fw2  = (const float*)d_in[12];
  const float* fb2  = (const float*)d_in[13];
  float* o = (float*)d_out;
  char* ws = (char*)d_ws;

  din_prep<<<dim3(192), dim3(256), 0, stream>>>(aw1, fw1, ws);
  din_main<<<dim3(512), dim3(512), 0, stream>>>(uf, tif, bseq, e0, e1, ei,
                                                ab1, aw2, ws);
  din_fc<<<dim3(256), dim3(256), 0, stream>>>(fb1, fw2, fb2, ws, o);
}

// Round 5
// 112.859 us; speedup vs baseline: 1.3086x; 1.3086x over previous
//
#include <hip/hip_runtime.h>
#include <math.h>

// DIN fused, round 5: DS-pipe diet.
//  - Scores: H = Beh@A' + (Beh(.)t)@D' + t@Bm + b1 ; A',D' frags in registers
//    (block-invariant!), beh(.)t built in-register. mfma_16x16x32_bf16.
//  - Score reduction over h via DPP (quad_perm/row_ror) — zero DS ops.
//  - 4-wave blocks, 4 b's each; wave = (h-half) x (s-parity).
//  k0 prep: A'T/D'T [h][d] bf16, Bm [d][h] bf16, fw1T pre-swizzled bf16.
//  k2 FC head unchanged (MFMA, 16 b/block).

#define S_LEN 200
#define S_PAD 208

typedef __attribute__((ext_vector_type(8))) short short8;
typedef __attribute__((ext_vector_type(4))) float f32x4;

__device__ __forceinline__ unsigned short f2b(float f) {
  union { float f; unsigned u; } x; x.f = f;
  unsigned r = x.u + 0x7fffu + ((x.u >> 16) & 1u);
  return (unsigned short)(r >> 16);
}
__device__ __forceinline__ float b2f(unsigned short h) {
  union { unsigned u; float f; } x; x.u = ((unsigned)h) << 16; return x.f;
}

// [row][64] bf16 tile, row stride 128 B (XOR row&7 into byte b4..6)
__device__ __forceinline__ int swzB(int row, int col) {
  int byte = row * 128 + col * 2;
  byte ^= (row & 7) << 4;
  return byte >> 1;
}
// [row][256] bf16 tile, row stride 512 B
__device__ __forceinline__ int swzW(int row, int col) {
  int byte = row * 512 + col * 2;
  byte ^= (row & 7) << 4;
  return byte >> 1;
}

__device__ __forceinline__ void async_g2l_16(const void* g, void* l) {
  __builtin_amdgcn_global_load_lds(
      (const __attribute__((address_space(1))) void*)g,
      (__attribute__((address_space(3))) void*)l, 16, 0, 0);
}

// DPP add: v += lane-permuted v. 16-lane butterfly: 0xB1(xor1), 0x4E(xor2),
// 0x124(row_ror:4), 0x128(row_ror:8) -> all 16 lanes hold the row sum.
template <int CTRL>
__device__ __forceinline__ float dpp_add(float v) {
  const int t = __builtin_amdgcn_mov_dpp(__float_as_int(v), CTRL, 0xF, 0xF, true);
  return v + __int_as_float(t);
}
__device__ __forceinline__ float rowReduce16(float v) {
  v = dpp_add<0xB1>(v);
  v = dpp_add<0x4E>(v);
  v = dpp_add<0x124>(v);
  v = dpp_add<0x128>(v);
  return v;
}
__device__ __forceinline__ float waveReduceSum(float v) {
#pragma unroll
  for (int m = 32; m; m >>= 1) v += __shfl_xor(v, m, 64);
  return v;
}

// ---------------- workspace layout (bytes) ----------------
#define WS_COMB 0          // bf16-swz [256 tiles][16][256]  (2 MB)
#define WS_AT   2097152    // A' = W1a+W1c, [h][d] bf16, 16 KB
#define WS_DT   2113536    // D' = W1d,     [h][d] bf16, 16 KB
#define WS_BM   2129920    // Bm = W1b-W1c, [d][h] bf16, 16 KB
#define WS_FW1T 2146304    // fw1^T pre-swizzled bf16, 64 KB

// ================= k0: prep =================
__global__ __launch_bounds__(256)
void din_prep(const float* __restrict__ aw1, const float* __restrict__ fw1,
              char* __restrict__ ws)
{
  unsigned short* AT   = (unsigned short*)(ws + WS_AT);
  unsigned short* DT   = (unsigned short*)(ws + WS_DT);
  unsigned short* Bm   = (unsigned short*)(ws + WS_BM);
  unsigned short* FW1T = (unsigned short*)(ws + WS_FW1T);
  const int blk = blockIdx.x, tid = threadIdx.x;

  if (blk < 32) {               // A'T, D'T : [h][d]
    const int i = blk * 256 + tid;
    const int h = i >> 6, d = i & 63;
    const float a = aw1[d * 128 + h];
    const float c = aw1[(128 + d) * 128 + h];
    const float dd = aw1[(192 + d) * 128 + h];
    AT[i] = f2b(a + c);
    DT[i] = f2b(dd);
  } else if (blk < 64) {        // Bm : [d][h]
    const int j = (blk - 32) * 256 + tid;
    const int d = j >> 7, h = j & 127;
    Bm[j] = f2b(aw1[(64 + d) * 128 + h] - aw1[(128 + d) * 128 + h]);
  } else {                      // fw1T swizzled image
    const int i = (blk - 64) * 256 + tid;
    const int o = 2 * i;
    const int h = o >> 9;
    const int rr = o & 511;
    const int d = (rr ^ ((h & 7) << 4)) >> 1;
    FW1T[i] = f2b(fw1[d * 128 + h]);
  }
}

// ================= k1: main =================
__global__ __launch_bounds__(256, 3)
void din_main(const int* __restrict__ uf, const int* __restrict__ tif,
              const int* __restrict__ bseq,
              const float* __restrict__ e0, const float* __restrict__ e1,
              const float* __restrict__ ei,
              const float* __restrict__ ab1, const float* __restrict__ aw2,
              char* __restrict__ ws)
{
  __shared__ unsigned short sBeh[13312];  // 26624 B; [0,16KB) aliased as Bm stage
  __shared__ int   sIdx[800];
  __shared__ float sT[256];               // 4 b x 64
  __shared__ float sCH[512];              // 4 b x 128
  __shared__ float sPart[2][S_PAD];       // 2 h-halves
  __shared__ float sScores[S_PAD];
  __shared__ float sPool[256];            // 4 waves x 64
  __shared__ float sRedS[4];

  unsigned short* combS = (unsigned short*)(ws + WS_COMB);
  const unsigned short* ATws = (const unsigned short*)(ws + WS_AT);
  const unsigned short* DTws = (const unsigned short*)(ws + WS_DT);

  const int tid  = threadIdx.x;
  const int lane = tid & 63;
  const int wv   = tid >> 6;
  const int hl   = lane & 15;      // h-in-tile / beh row-in-tile
  const int rq   = lane >> 4;      // k-octet / output row quad
  const int H    = wv & 1;         // h-half (0: h<64, 1: h>=64)
  const int sv   = wv >> 1;        // s-tile parity
  const int bb   = blockIdx.x * 4;

  // ---- prologue ----
  for (int k = tid; k < 800; k += 256) sIdx[k] = bseq[bb * 200 + k];
  {
    const int g = tid >> 6, d = tid & 63, b = bb + g;
    const int u0 = uf[2 * b], u1 = uf[2 * b + 1], ti = tif[b];
    const float tv = ei[(size_t)ti * 64 + d];
    sT[g * 64 + d] = tv;
    unsigned short* ct = combS + (size_t)(b >> 4) * 4096;
    const int row = b & 15;
    ct[swzW(row, 192 + d)] = f2b(tv);
    ct[swzW(row, d)]       = f2b(e0[(size_t)u0 * 64 + d]);
    ct[swzW(row, 64 + d)]  = f2b(e1[(size_t)u1 * 64 + d]);
  }
  if (tid < 128) {   // zero pad rows 200..207 (bytes 25600+, disjoint from Bm)
    const int row = 200 + (tid >> 4), c = (tid & 15) * 4;
    ushort4 z = {0, 0, 0, 0};
    *(ushort4*)&sBeh[swzB(row, c)] = z;
  }
  {  // stage Bm (16 KB, plain [d][h]) into sBeh low region
    char* dst = (char*)sBeh;
    const char* src = ws + WS_BM;
#pragma unroll
    for (int it = 0; it < 4; ++it)
      async_g2l_16(src + it * 4096 + tid * 16, dst + it * 4096 + tid * 16);
  }
  // block-invariant B-fragments: A'/D' for this wave's h-half (64 VGPR)
  short8 aF[4][2], dF[4][2];
  float w2r[4], abr[4];
#pragma unroll
  for (int ht = 0; ht < 4; ++ht) {
    const int hh = H * 64 + ht * 16 + hl;
#pragma unroll
    for (int kk = 0; kk < 2; ++kk) {
      aF[ht][kk] = *(const short8*)(ATws + hh * 64 + kk * 32 + rq * 8);
      dF[ht][kk] = *(const short8*)(DTws + hh * 64 + kk * 32 + rq * 8);
    }
    w2r[ht] = aw2[hh];
    abr[ht] = ab1[hh];
  }
  __syncthreads();  // Bm staged, sT/sIdx/pad ready

  // ---- cH[b][h2] = t[b] . Bm[:,h2] ----
  {
    const unsigned short* sBm = sBeh;
    const int h2 = tid & 127, bq = tid >> 7;   // bq -> b pair {2bq, 2bq+1}
    float c0 = 0.f, c1 = 0.f;
    const float* t0 = sT + (2 * bq) * 64;
    const float* t1 = sT + (2 * bq + 1) * 64;
#pragma unroll 8
    for (int d = 0; d < 64; ++d) {
      const float bmv = b2f(sBm[d * 128 + h2]);
      c0 = fmaf(t0[d], bmv, c0);
      c1 = fmaf(t1[d], bmv, c1);
    }
    sCH[(2 * bq) * 128 + h2] = c0;
    sCH[(2 * bq + 1) * 128 + h2] = c1;
  }
  __syncthreads();  // cH ready; Bm region now free

  // ---- per-b loop (4 barriers each) ----
  for (int g = 0; g < 4; ++g) {
    const int b = bb + g;

    // gather + commit (bf16, swizzled)
#pragma unroll 1
    for (int it = 0; it < 13; ++it) {
      const int row = it * 16 + (tid >> 4);
      if (row < S_LEN) {
        const int idx = sIdx[g * 200 + row];
        const float4 v = *(const float4*)(ei + (size_t)idx * 64 + (tid & 15) * 4);
        ushort4 pk;
        pk.x = f2b(v.x); pk.y = f2b(v.y); pk.z = f2b(v.z); pk.w = f2b(v.w);
        *(ushort4*)&sBeh[swzB(row, (tid & 15) * 4)] = pk;
      }
    }

    // per-lane t values at this lane's k-positions (for beh(.)t)
    float tt0[8], tt1[8];
    {
      const float* tb = sT + g * 64;
      const float4 a0 = *(const float4*)(tb + rq * 8);
      const float4 a1 = *(const float4*)(tb + rq * 8 + 4);
      const float4 c0 = *(const float4*)(tb + 32 + rq * 8);
      const float4 c1 = *(const float4*)(tb + 32 + rq * 8 + 4);
      tt0[0]=a0.x; tt0[1]=a0.y; tt0[2]=a0.z; tt0[3]=a0.w;
      tt0[4]=a1.x; tt0[5]=a1.y; tt0[6]=a1.z; tt0[7]=a1.w;
      tt1[0]=c0.x; tt1[1]=c0.y; tt1[2]=c0.z; tt1[3]=c0.w;
      tt1[4]=c1.x; tt1[5]=c1.y; tt1[6]=c1.z; tt1[7]=c1.w;
    }
    float cHr[4];
#pragma unroll
    for (int ht = 0; ht < 4; ++ht)
      cHr[ht] = sCH[g * 128 + H * 64 + ht * 16 + hl] + abr[ht];

    __syncthreads();  // (1) beh ready

    // MFMA phase: this wave's s-tiles (parity sv), h-half H
#pragma unroll 1
    for (int tile = sv; tile < 13; tile += 2) {
      const short8 av0 = *(const short8*)&sBeh[swzB(tile * 16 + hl, rq * 8)];
      const short8 av1 = *(const short8*)&sBeh[swzB(tile * 16 + hl, 32 + rq * 8)];
      // beh (.) t in-register
      union { short8 s; unsigned u[4]; } m0, m1;
#pragma unroll
      for (int p = 0; p < 4; ++p) {
        float lo0 = b2f((unsigned short)av0[2*p])   * tt0[2*p];
        float hi0 = b2f((unsigned short)av0[2*p+1]) * tt0[2*p+1];
        m0.u[p] = (unsigned)f2b(lo0) | ((unsigned)f2b(hi0) << 16);
        float lo1 = b2f((unsigned short)av1[2*p])   * tt1[2*p];
        float hi1 = b2f((unsigned short)av1[2*p+1]) * tt1[2*p+1];
        m1.u[p] = (unsigned)f2b(lo1) | ((unsigned)f2b(hi1) << 16);
      }
      float sc[4] = {0.f, 0.f, 0.f, 0.f};
#pragma unroll
      for (int ht = 0; ht < 4; ++ht) {
        f32x4 acc = {0.f, 0.f, 0.f, 0.f};
        acc = __builtin_amdgcn_mfma_f32_16x16x32_bf16(av0, aF[ht][0], acc, 0, 0, 0);
        acc = __builtin_amdgcn_mfma_f32_16x16x32_bf16(av1, aF[ht][1], acc, 0, 0, 0);
        acc = __builtin_amdgcn_mfma_f32_16x16x32_bf16(m0.s, dF[ht][0], acc, 0, 0, 0);
        acc = __builtin_amdgcn_mfma_f32_16x16x32_bf16(m1.s, dF[ht][1], acc, 0, 0, 0);
#pragma unroll
        for (int r = 0; r < 4; ++r)
          sc[r] += fmaxf(acc[r] + cHr[ht], 0.f) * w2r[ht];
      }
      // reduce over the 16 h-lanes (DPP, no DS ops)
#pragma unroll
      for (int r = 0; r < 4; ++r) {
        sc[r] = rowReduce16(sc[r]);
        if (hl == 0) sPart[H][tile * 16 + rq * 4 + r] = sc[r];
      }
    }
    __syncthreads();  // (2) partials ready

    // combine halves + exp (no max-shift; shift-invariant, |s| small)
    float e = 0.f;
    if (tid < S_LEN) {
      e = __expf(sPart[0][tid] + sPart[1][tid]);
      sScores[tid] = e;
    }
    {
      float s = waveReduceSum(e);
      if (lane == 0) sRedS[wv] = s;
    }
    __syncthreads();  // (3) sScores + wave sums ready

    const float invS = 1.f / (sRedS[0] + sRedS[1] + sRedS[2] + sRedS[3]);

    // pooling: wave takes 4-aligned score chunks c = wv, wv+4, ...
    {
      float pool = 0.f;
#pragma unroll 1
      for (int c = wv; c < 50; c += 4) {
        const int s0 = c * 4;
        const float4 sv4 = *(const float4*)&sScores[s0];
        pool = fmaf(sv4.x, b2f(sBeh[swzB(s0,     lane)]), pool);
        pool = fmaf(sv4.y, b2f(sBeh[swzB(s0 + 1, lane)]), pool);
        pool = fmaf(sv4.z, b2f(sBeh[swzB(s0 + 2, lane)]), pool);
        pool = fmaf(sv4.w, b2f(sBeh[swzB(s0 + 3, lane)]), pool);
      }
      sPool[wv * 64 + lane] = pool;
    }
    __syncthreads();  // (4) sPool ready; sBeh free for next b

    if (tid < 64) {
      const float a = sPool[tid] + sPool[64 + tid] + sPool[128 + tid] + sPool[192 + tid];
      combS[(size_t)(b >> 4) * 4096 + swzW(b & 15, 128 + tid)] = f2b(a * invS);
    }
  }
}

// ================= k2: FC head =================
__global__ __launch_bounds__(256, 2)
void din_fc(const float* __restrict__ fb1, const float* __restrict__ fw2,
            const float* __restrict__ fb2, const char* __restrict__ ws,
            float* __restrict__ out)
{
  __shared__ unsigned short sW[32768];   // fw1T swizzled image, 64 KB
  __shared__ unsigned short sA[4096];    // comb tile (pre-swizzled bf16), 8 KB
  __shared__ float sO[64];

  const int tid  = threadIdx.x;
  const int lane = tid & 63;
  const int wv   = tid >> 6;
  const int bb   = blockIdx.x * 16;

  {
    const char* srcW = ws + WS_FW1T;
    char* dstW = (char*)sW;
#pragma unroll
    for (int it = 0; it < 16; ++it)
      async_g2l_16(srcW + it * 4096 + tid * 16, dstW + it * 4096 + tid * 16);
    const char* srcA = ws + WS_COMB + (size_t)blockIdx.x * 8192;
    char* dstA = (char*)sA;
    async_g2l_16(srcA + tid * 16, dstA + tid * 16);
    async_g2l_16(srcA + 4096 + tid * 16, dstA + 4096 + tid * 16);
  }
  __syncthreads();

  const int hl = lane & 15, rq = lane >> 4;
  const int h0 = wv * 32 + hl, h1 = h0 + 16;
  f32x4 acc0 = {0.f, 0.f, 0.f, 0.f};
  f32x4 acc1 = {0.f, 0.f, 0.f, 0.f};
#pragma unroll
  for (int kk = 0; kk < 8; ++kk) {
    const short8 av = *(const short8*)&sA[swzW(hl, kk * 32 + rq * 8)];
    const short8 b0 = *(const short8*)&sW[swzW(h0, kk * 32 + rq * 8)];
    const short8 b1 = *(const short8*)&sW[swzW(h1, kk * 32 + rq * 8)];
    acc0 = __builtin_amdgcn_mfma_f32_16x16x32_bf16(av, b0, acc0, 0, 0, 0);
    acc1 = __builtin_amdgcn_mfma_f32_16x16x32_bf16(av, b1, acc1, 0, 0, 0);
  }
  const float fb10 = fb1[h0], fb11 = fb1[h1];
  const float fw20 = fw2[h0], fw21 = fw2[h1];
#pragma unroll
  for (int r = 0; r < 4; ++r) {
    float v = fmaxf(acc0[r] + fb10, 0.f) * fw20
            + fmaxf(acc1[r] + fb11, 0.f) * fw21;
    v += __shfl_xor(v, 1, 64);
    v += __shfl_xor(v, 2, 64);
    v += __shfl_xor(v, 4, 64);
    v += __shfl_xor(v, 8, 64);
    if (hl == 0) sO[wv * 16 + rq * 4 + r] = v;
  }
  __syncthreads();
  if (tid < 16)
    out[bb + tid] = sO[tid] + sO[16 + tid] + sO[32 + tid] + sO[48 + tid] + fb2[0];
}

extern "C" void kernel_launch(void* const* d_in, const int* in_sizes, int n_in,
                              void* d_out, int out_size, void* d_ws, size_t ws_size,
                              hipStream_t stream) {
  const int*   uf   = (const int*)d_in[0];
  const int*   tif  = (const int*)d_in[1];
  const int*   bseq = (const int*)d_in[2];
  const float* e0   = (const float*)d_in[3];
  const float* e1   = (const float*)d_in[4];
  const float* ei   = (const float*)d_in[5];
  const float* aw1  = (const float*)d_in[6];
  const float* ab1  = (const float*)d_in[7];
  const float* aw2  = (const float*)d_in[8];
  // d_in[9] = ab2 (unused: softmax shift-invariant)
  const float* fw1  = (const float*)d_in[10];
  const float* fb1  = (const float*)d_in[11];
  const float* fw2  = (const float*)d_in[12];
  const float* fb2  = (const float*)d_in[13];
  float* o = (float*)d_out;
  char* ws = (char*)d_ws;

  din_prep<<<dim3(192), dim3(256), 0, stream>>>(aw1, fw1, ws);
  din_main<<<dim3(1024), dim3(256), 0, stream>>>(uf, tif, bseq, e0, e1, ei,
                                                 ab1, aw2, ws);
  din_fc<<<dim3(256), dim3(256), 0, stream>>>(fb1, fw2, fb2, ws, o);
}